// Round 6
// baseline (148.890 us; speedup 1.0000x reference)
//
#include <hip/hip_runtime.h>
#include <hip/hip_bf16.h>

// ============================================================================
// indices ∈ [0,64) => backbone + theta have only 64 distinct rows. Compute
// per-class (7 MB, L2-resident), bucket batches by class, run only the tiny
// per-batch MLPs with class-shared weights.
// R10: K3 v10 — R9 layout (all weights resident, 156.6KB LDS, CAP 44, fused
// f-L2, W3f transposed, async global_load_lds staging) but W2f staging
// PIPELINED into the pass: wH issued after B1 (drains B2, covered by e-L1),
// wH2 issued after B2 (drains B3, covered by e-L2). This restores the
// staging/compute overlap that made R7 faster than R8/R9 (both of which
// serialized the full 108KB fetch before any compute). Pre-loop staging is
// only 10.7KB. K0/K1/K2 unchanged.
// ============================================================================

#define LEAKY 0.2f
#define NCLS 64
#define B_TOT 8192
#define CAP 44            // batches per K3 pass (capacity)

// theta_e (per class, 5456 fl): W1e[0,128) b1e[128,192) W2e[192,4288)
//   b2e[4288,4352) W3e[4352,5376) b3e[5376,5392)
// theta_f (per class, 21768 fl): W1f[0,4096) b1f[4096,4224) W2f[4224,20608)
//   b2f[20608,20736) W3f[20736,21760) b3f[21760,21768)

__device__ __forceinline__ float lrelu(float x) { return x >= 0.f ? x : LEAKY * x; }

// async global->LDS, 16B per lane; LDS dest = wave-uniform base + lane*16
#define GLDS(gp, lp) __builtin_amdgcn_global_load_lds(                        \
    (const __attribute__((address_space(1))) void*)(gp),                      \
    (__attribute__((address_space(3))) void*)(lp), 16, 0, 0)

// ---------------------------------------------------------------------------
// K0: fc1 1024->256 split over 256 blocks: block = (class c = bx>>2, quarter
// q = bx&3). 1024 thr: o = q*64 + (t&63), 16 K-slices of 64.
// ---------------------------------------------------------------------------
__global__ __launch_bounds__(1024) void fc1_kernel(
    const float* __restrict__ maps, const float* __restrict__ fc1_w,
    const float* __restrict__ fc1_b, float* __restrict__ h1g)
{
    __shared__ float m[1024];
    __shared__ float red[1024];
    const int t = threadIdx.x;
    const int c = blockIdx.x >> 2;
    const int q = blockIdx.x & 3;

    m[t] = maps[(size_t)c * 1024 + t];
    __syncthreads();

    const int ol = t & 63, ks = t >> 6;
    const int o = q * 64 + ol;
    const float* wp = fc1_w + o;
    float acc = 0.f;
#pragma unroll 8
    for (int i = 0; i < 64; ++i) {
        const int k = ks * 64 + i;
        acc += m[k] * wp[(size_t)k * 256];
    }
    red[t] = acc;
    __syncthreads();
    if (t < 64) {
        float a = fc1_b[q * 64 + t];
#pragma unroll
        for (int r = 0; r < 16; ++r) a += red[r * 64 + t];
        h1g[c * 256 + q * 64 + t] = lrelu(a);
    }
}

// ---------------------------------------------------------------------------
// K1: blocks 0..63: fc2+fc3+bn for class c (h1 from ws). block 64: bucket.
// ---------------------------------------------------------------------------
__global__ __launch_bounds__(1024) void backbone_bucket_kernel(
    const float* __restrict__ h1g,
    const float* __restrict__ fc2_w, const float* __restrict__ fc2_b,
    const float* __restrict__ fc3_w, const float* __restrict__ fc3_b,
    const float* __restrict__ bn_w,  const float* __restrict__ bn_b,
    float* __restrict__ z,
    const int* __restrict__ idx, int* __restrict__ counts,
    int* __restrict__ offsets, int* __restrict__ perm)
{
    __shared__ float red[1024];
    __shared__ float h1[256];
    __shared__ float h2[128];
    __shared__ float h3[128];
    __shared__ int cnt[16][64];
    __shared__ int wcur[16][64];

    const int t = threadIdx.x;

    if (blockIdx.x == 64) {
        // ---------------- bucket ----------------
        const int w = t >> 6;
        cnt[w][t & 63] = 0;
        __syncthreads();
        int my[8];
#pragma unroll
        for (int r = 0; r < 8; ++r) {
            my[r] = idx[r * 1024 + t];
            atomicAdd(&cnt[w][my[r]], 1);
        }
        __syncthreads();
        if (t < 64) {
            int run = 0;
#pragma unroll
            for (int w2 = 0; w2 < 16; ++w2) {
                const int v = cnt[w2][t];
                wcur[w2][t] = run;
                run += v;
            }
            counts[t] = run;
            int x = run;
            for (int d = 1; d < 64; d <<= 1) {
                const int y = __shfl_up(x, d, 64);
                if (t >= d) x += y;
            }
            const int basec = x - run;
            offsets[t] = basec;
#pragma unroll
            for (int w2 = 0; w2 < 16; ++w2) wcur[w2][t] += basec;
        }
        __syncthreads();
#pragma unroll
        for (int r = 0; r < 8; ++r) {
            const int p = atomicAdd(&wcur[w][my[r]], 1);
            perm[p] = r * 1024 + t;
        }
        return;
    }

    // ---------------- fc2/fc3/bn for class c ----------------
    const int c = blockIdx.x;
    if (t < 256) h1[t] = h1g[c * 256 + t];
    __syncthreads();

    // fc2: 256 -> 128 (leaky)
    {
        const int o = t & 127, ks = t >> 7;
        float acc = 0.f;
#pragma unroll
        for (int i = 0; i < 32; ++i) {
            const int k = ks * 32 + i;
            acc += h1[k] * fc2_w[k * 128 + o];
        }
        red[t] = acc;
    }
    __syncthreads();
    if (t < 128) {
        float a = fc2_b[t];
#pragma unroll
        for (int r = 0; r < 8; ++r) a += red[r * 128 + t];
        h2[t] = lrelu(a);
    }
    __syncthreads();
    // fc3: 128 -> 128 (leaky)
    {
        const int o = t & 127, ks = t >> 7;
        float acc = 0.f;
#pragma unroll
        for (int i = 0; i < 16; ++i) {
            const int k = ks * 16 + i;
            acc += h2[k] * fc3_w[k * 128 + o];
        }
        red[t] = acc;
    }
    __syncthreads();
    if (t < 128) {
        float a = fc3_b[t];
#pragma unroll
        for (int r = 0; r < 8; ++r) a += red[r * 128 + t];
        h3[t] = lrelu(a);
    }
    __syncthreads();
    // bn: 128 -> 32 (no act)
    {
        const int o = t & 31, ks = t >> 5;
        float acc = 0.f;
#pragma unroll
        for (int i = 0; i < 4; ++i) {
            const int k = ks * 4 + i;
            acc += h3[k] * bn_w[k * 32 + o];
        }
        red[t] = acc;
    }
    __syncthreads();
    if (t < 32) {
        float a = bn_b[t];
#pragma unroll
        for (int r = 0; r < 32; ++r) a += red[r * 32 + t];
        z[c * 32 + t] = a;
    }
}

// ---------------------------------------------------------------------------
// K2: theta, grid (107, 8): block owns 256 cols x 8 classes. Weights in regs.
// ---------------------------------------------------------------------------
__global__ __launch_bounds__(256) void theta_kernel(
    const float* __restrict__ z,
    const float* __restrict__ e_w, const float* __restrict__ e_b,
    const float* __restrict__ f_w, const float* __restrict__ f_b,
    float* __restrict__ th_e, float* __restrict__ th_f)
{
    __shared__ __align__(16) float zl[2048];
    const int t = threadIdx.x;
    ((float4*)zl)[t]       = ((const float4*)z)[t];
    ((float4*)zl)[t + 256] = ((const float4*)z)[t + 256];
    __syncthreads();

    int j = blockIdx.x * 256 + t;
    const int cbase = blockIdx.y * 8;
    const float* wbase;
    float* op;
    int stride;
    float bias;
    if (j < 5456) {
        wbase = e_w + j; bias = e_b[j]; op = th_e + j; stride = 5456;
    } else {
        const int jj = j - 5456;
        if (jj >= 21768) return;
        wbase = f_w + jj; bias = f_b[jj]; op = th_f + jj; stride = 21768;
    }
    float wk[32];
#pragma unroll
    for (int k = 0; k < 32; ++k) wk[k] = wbase[(size_t)k * stride];

#pragma unroll
    for (int cc = 0; cc < 8; cc += 4) {
        const int c0 = cbase + cc;
        float a0 = bias, a1 = bias, a2 = bias, a3 = bias;
#pragma unroll
        for (int k4 = 0; k4 < 8; ++k4) {
            const float4 z0 = *(const float4*)&zl[(c0 + 0) * 32 + k4 * 4];
            const float4 z1 = *(const float4*)&zl[(c0 + 1) * 32 + k4 * 4];
            const float4 z2 = *(const float4*)&zl[(c0 + 2) * 32 + k4 * 4];
            const float4 z3 = *(const float4*)&zl[(c0 + 3) * 32 + k4 * 4];
            const float w0 = wk[k4 * 4], w1 = wk[k4 * 4 + 1];
            const float w2 = wk[k4 * 4 + 2], w3 = wk[k4 * 4 + 3];
            a0 += z0.x * w0 + z0.y * w1 + z0.z * w2 + z0.w * w3;
            a1 += z1.x * w0 + z1.y * w1 + z1.z * w2 + z1.w * w3;
            a2 += z2.x * w0 + z2.y * w1 + z2.z * w2 + z2.w * w3;
            a3 += z3.x * w0 + z3.y * w1 + z3.z * w2 + z3.w * w3;
        }
        op[(size_t)(c0 + 0) * stride] = a0;
        op[(size_t)(c0 + 1) * stride] = a1;
        op[(size_t)(c0 + 2) * stride] = a2;
        op[(size_t)(c0 + 3) * stride] = a3;
    }
}

// ---------------------------------------------------------------------------
// K3: func v10. grid (64, 4), 512 thr. Slice s = balanced ~nb/4 chunk, one
// pass of capacity 44 (3 batches/thread with tail guards). ALL weights
// LDS-resident; wE/W1f/tails staged pre-loop (10.7KB), W2f halves staged
// INSIDE the pass overlapped with e-L1 / e-L2 compute; 6 barriers/pass.
// LDS (floats):
//   wE  [0,     5392)  theta_e complete
//   wFa [5392,  9616)  W1f | b1f
//   wFb2[9616,  9744)  b2f
//   wFb3[9744,  9752)  b3f
//   wT  [9752, 10808)  W3f transposed: [col]*132 + k
//   wH  [10808,19000)  W2f k-rows 0..63   (staged after B1, pass 0)
//   wH2 [19000,27192)  W2f k-rows 64..127 (staged after B2, pass 0)
//   actA[27192,33176)  (5984 = 88*68) / actB[33176,39160)
//   total 39160 fl = 156640 B (dynamic, opt-in)
// e phases (t<256): eg=t&7 (8 col grps), vp=t>>3; vb = vp+{0,32,64}, vb<88.
// f phases (t<256): bp=t&15, fg=t>>4 (16 col grps); fb = bp+{0,16,32}, fb<44.
// f-L3 (t<352): col8=t&7, fb3=t>>3.
// ---------------------------------------------------------------------------
#define ESTRIDE 68   // 17 float4s, odd -> conflict-free
#define FSTRIDE 132  // 33 float4s, odd

#define K3_LDS_FLOATS 39160
#define K3_LDS_BYTES  (K3_LDS_FLOATS * 4)

__global__ __launch_bounds__(512) void func_kernel(
    const float* __restrict__ states,
    const float* __restrict__ th_e_all, const float* __restrict__ th_f_all,
    const int* __restrict__ counts, const int* __restrict__ offsets,
    const int* __restrict__ perm, float* __restrict__ out)
{
    extern __shared__ float smem[];
    float* wE   = smem;             // 5392
    float* wFa  = smem + 5392;      // 4224
    float* wFb2 = smem + 9616;      // 128
    float* wFb3 = smem + 9744;      // 8
    float* wT   = smem + 9752;      // 1056
    float* wH   = smem + 10808;     // 8192
    float* wH2  = smem + 19000;     // 8192
    float* actA = smem + 27192;     // 5984
    float* actB = smem + 33176;     // 5984

    const int c = blockIdx.x;
    const int s = blockIdx.y;
    const int nb   = counts[c];
    const int base = offsets[c];
    const int q = nb >> 2, r = nb & 3;
    const int lo  = s * q + (s < r ? s : r);
    const int cnt = q + (s < r ? 1 : 0);
    if (cnt == 0) return;
    const int hi = lo + cnt;

    const float* te = th_e_all + (size_t)c * 5456;
    const float* tf = th_f_all + (size_t)c * 21768;

    const int t  = threadIdx.x;
    const int eg = t & 7,  vp = t >> 3;    // e mapping (valid t<256)
    const int bp = t & 15, fg = t >> 4;    // f mapping (valid t<256)
    const int cole = eg * 8;
    const int colf = fg * 8;
    const int col8 = t & 7, fb3 = t >> 3;  // f-L3 mapping (valid t<352)
    const bool e_has2 = (vp < 24);         // third e-sub valid (vb=vp+64<88)
    const bool f_has2 = (bp < 12);         // third f-sub valid (fb=bp+32<44)

    // ---- W3f scalar loads first (oldest in vmem queue) ----
    const float w3a = tf[20736 + t];
    const float w3b = tf[20736 + 512 + t];

    // ---- pre-loop staging: only what's needed by B2 (10.7KB) ----
    for (int j = t * 4; j < 5392; j += 2048) GLDS(te + j,         wE  + j);
    for (int j = t * 4; j < 4224; j += 2048) GLDS(tf + j,         wFa + j);
    if (t < 32) GLDS(tf + 20608 + t * 4, wFb2 + t * 4);
    if (t < 2)  GLDS(tf + 21760 + t * 4, wFb3 + t * 4);

    // ---- prefetch perm/states for pass 0 (drained at B1 with everything) --
    float2 sv0 = {0.f, 0.f}, sv1 = {0.f, 0.f}, sv2 = {0.f, 0.f};
    if (t < 256) {
        const int ve2 = (vp & 1) * 2;
        int ib = lo + (vp >> 1);
        int bi = (ib < hi) ? perm[base + ib] : 0;
        sv0 = *(const float2*)&states[(size_t)bi * 4 + ve2];
        ib = lo + ((vp + 32) >> 1);
        bi = (ib < hi) ? perm[base + ib] : 0;
        sv1 = *(const float2*)&states[(size_t)bi * 4 + ve2];
        ib = lo + ((vp + 64) >> 1);
        bi = (ib < hi) ? perm[base + ib] : 0;
        sv2 = *(const float2*)&states[(size_t)bi * 4 + ve2];
    }

    // ---- W3f transpose writes (waits only its own 2 scalar loads) ----
    wT[( t        & 7) * 132 + ( t        >> 3)] = w3a;
    wT[((t + 512) & 7) * 132 + ((t + 512) >> 3)] = w3b;

    const int npass = (cnt + CAP - 1) / CAP;   // 1 in practice
    for (int p = 0; p < npass; ++p) {
        __syncthreads();   // B1: drains pre-loop staging (p=0) / prev reads

        // W2f half 0: issued here, drains at B2 (covered by e-L1), used B5+
        if (p == 0)
            for (int j = t * 4; j < 8192; j += 2048) GLDS(tf + 4224 + j, wH + j);

        const int pb = lo + p * CAP;   // first class-local batch this pass

        if (p && t < 256) {            // reload sv* for later passes (rare)
            const int ve2 = (vp & 1) * 2;
            int ib = pb + (vp >> 1);
            int bi = (ib < hi) ? perm[base + ib] : 0;
            sv0 = *(const float2*)&states[(size_t)bi * 4 + ve2];
            ib = pb + ((vp + 32) >> 1);
            bi = (ib < hi) ? perm[base + ib] : 0;
            sv1 = *(const float2*)&states[(size_t)bi * 4 + ve2];
            ib = pb + ((vp + 64) >> 1);
            bi = (ib < hi) ? perm[base + ib] : 0;
            sv2 = *(const float2*)&states[(size_t)bi * 4 + ve2];
        }

        // ---- e-L1: 2 -> 64 (leaky), up to 3 vb/thread ----
        if (t < 256) {
            const float4 wa0 = *(const float4*)&wE[cole];
            const float4 wa1 = *(const float4*)&wE[cole + 4];
            const float4 wb0 = *(const float4*)&wE[64 + cole];
            const float4 wb1 = *(const float4*)&wE[64 + cole + 4];
            const float4 bb0 = *(const float4*)&wE[128 + cole];
            const float4 bb1 = *(const float4*)&wE[128 + cole + 4];
#define E_L1_SUB(SV, OFF, GUARD)                                              \
            if (GUARD) {                                                      \
                const int vb = vp + OFF;                                      \
                float4 o0, o1;                                                \
                o0.x = lrelu(SV.x * wa0.x + SV.y * wb0.x + bb0.x);            \
                o0.y = lrelu(SV.x * wa0.y + SV.y * wb0.y + bb0.y);            \
                o0.z = lrelu(SV.x * wa0.z + SV.y * wb0.z + bb0.z);            \
                o0.w = lrelu(SV.x * wa0.w + SV.y * wb0.w + bb0.w);            \
                o1.x = lrelu(SV.x * wa1.x + SV.y * wb1.x + bb1.x);            \
                o1.y = lrelu(SV.x * wa1.y + SV.y * wb1.y + bb1.y);            \
                o1.z = lrelu(SV.x * wa1.z + SV.y * wb1.z + bb1.z);            \
                o1.w = lrelu(SV.x * wa1.w + SV.y * wb1.w + bb1.w);            \
                *(float4*)&actA[vb * ESTRIDE + cole]     = o0;                \
                *(float4*)&actA[vb * ESTRIDE + cole + 4] = o1;                \
            }
            E_L1_SUB(sv0, 0,  true)
            E_L1_SUB(sv1, 32, true)
            E_L1_SUB(sv2, 64, e_has2)
#undef E_L1_SUB
        }
        __syncthreads();   // B2: drains wH staging

        // W2f half 1: issued here, drains at B3 (covered by e-L2), used B5+
        if (p == 0)
            for (int j = t * 4; j < 8192; j += 2048) GLDS(tf + 12416 + j, wH2 + j);

        // ---- e-L2: 64 -> 64 (leaky), up to 3 vb/thread ----
        if (t < 256) {
            const int e0 = vp * ESTRIDE;
            const int e1 = (vp + 32) * ESTRIDE;
            const int e2 = e_has2 ? (vp + 64) * ESTRIDE : e0;
            float a0[8] = {0,0,0,0,0,0,0,0};
            float a1[8] = {0,0,0,0,0,0,0,0};
            float a2[8] = {0,0,0,0,0,0,0,0};
#pragma unroll 4
            for (int i4 = 0; i4 < 16; ++i4) {
                const float4 y0 = *(const float4*)&actA[e0 + i4 * 4];
                const float4 y1 = *(const float4*)&actA[e1 + i4 * 4];
                const float4 y2 = *(const float4*)&actA[e2 + i4 * 4];
#pragma unroll
                for (int u = 0; u < 4; ++u) {
                    const int row = 192 + (i4 * 4 + u) * 64 + cole;
                    const float4 wA = *(const float4*)&wE[row];
                    const float4 wB = *(const float4*)&wE[row + 4];
                    const float v0 = (&y0.x)[u], v1 = (&y1.x)[u], v2 = (&y2.x)[u];
                    a0[0] += v0 * wA.x; a0[1] += v0 * wA.y;
                    a0[2] += v0 * wA.z; a0[3] += v0 * wA.w;
                    a0[4] += v0 * wB.x; a0[5] += v0 * wB.y;
                    a0[6] += v0 * wB.z; a0[7] += v0 * wB.w;
                    a1[0] += v1 * wA.x; a1[1] += v1 * wA.y;
                    a1[2] += v1 * wA.z; a1[3] += v1 * wA.w;
                    a1[4] += v1 * wB.x; a1[5] += v1 * wB.y;
                    a1[6] += v1 * wB.z; a1[7] += v1 * wB.w;
                    a2[0] += v2 * wA.x; a2[1] += v2 * wA.y;
                    a2[2] += v2 * wA.z; a2[3] += v2 * wA.w;
                    a2[4] += v2 * wB.x; a2[5] += v2 * wB.y;
                    a2[6] += v2 * wB.z; a2[7] += v2 * wB.w;
                }
            }
            const float4 bA = *(const float4*)&wE[4288 + cole];
            const float4 bB = *(const float4*)&wE[4288 + cole + 4];
            float4 o0, o1;
            o0.x = lrelu(a0[0] + bA.x); o0.y = lrelu(a0[1] + bA.y);
            o0.z = lrelu(a0[2] + bA.z); o0.w = lrelu(a0[3] + bA.w);
            o1.x = lrelu(a0[4] + bB.x); o1.y = lrelu(a0[5] + bB.y);
            o1.z = lrelu(a0[6] + bB.z); o1.w = lrelu(a0[7] + bB.w);
            *(float4*)&actB[e0 + cole]     = o0;
            *(float4*)&actB[e0 + cole + 4] = o1;
            o0.x = lrelu(a1[0] + bA.x); o0.y = lrelu(a1[1] + bA.y);
            o0.z = lrelu(a1[2] + bA.z); o0.w = lrelu(a1[3] + bA.w);
            o1.x = lrelu(a1[4] + bB.x); o1.y = lrelu(a1[5] + bB.y);
            o1.z = lrelu(a1[6] + bB.z); o1.w = lrelu(a1[7] + bB.w);
            *(float4*)&actB[e1 + cole]     = o0;
            *(float4*)&actB[e1 + cole + 4] = o1;
            if (e_has2) {
                o0.x = lrelu(a2[0] + bA.x); o0.y = lrelu(a2[1] + bA.y);
                o0.z = lrelu(a2[2] + bA.z); o0.w = lrelu(a2[3] + bA.w);
                o1.x = lrelu(a2[4] + bB.x); o1.y = lrelu(a2[5] + bB.y);
                o1.z = lrelu(a2[6] + bB.z); o1.w = lrelu(a2[7] + bB.w);
                *(float4*)&actB[e2 + cole]     = o0;
                *(float4*)&actB[e2 + cole + 4] = o1;
            }
        }
        __syncthreads();   // B3: drains wH2 staging

        // ---- e-L3: 64 -> 16 (no act) -> zf (f-layout in actA) ----
        if (t < 256) {
            const int col3 = eg * 2;
            const int e0 = vp * ESTRIDE;
            const int e1 = (vp + 32) * ESTRIDE;
            const int e2 = e_has2 ? (vp + 64) * ESTRIDE : e0;
            float a00 = 0.f, a01 = 0.f, a10 = 0.f, a11 = 0.f, a20 = 0.f, a21 = 0.f;
#pragma unroll 4
            for (int i4 = 0; i4 < 16; ++i4) {
                const float4 y0 = *(const float4*)&actB[e0 + i4 * 4];
                const float4 y1 = *(const float4*)&actB[e1 + i4 * 4];
                const float4 y2 = *(const float4*)&actB[e2 + i4 * 4];
#pragma unroll
                for (int u = 0; u < 4; ++u) {
                    const float2 w2 = *(const float2*)&wE[4352 + (i4 * 4 + u) * 16 + col3];
                    const float v0 = (&y0.x)[u], v1 = (&y1.x)[u], v2 = (&y2.x)[u];
                    a00 += v0 * w2.x; a01 += v0 * w2.y;
                    a10 += v1 * w2.x; a11 += v1 * w2.y;
                    a20 += v2 * w2.x; a21 += v2 * w2.y;
                }
            }
            const float b0 = wE[5376 + col3], b1 = wE[5376 + col3 + 1];
            {
                const int vb = vp, fb = vb >> 1, ve = vb & 1;
                actA[fb * FSTRIDE + ve * 16 + col3]     = a00 + b0;
                actA[fb * FSTRIDE + ve * 16 + col3 + 1] = a01 + b1;
            }
            {
                const int vb = vp + 32, fb = vb >> 1, ve = vb & 1;
                actA[fb * FSTRIDE + ve * 16 + col3]     = a10 + b0;
                actA[fb * FSTRIDE + ve * 16 + col3 + 1] = a11 + b1;
            }
            if (e_has2) {
                const int vb = vp + 64, fb = vb >> 1, ve = vb & 1;
                actA[fb * FSTRIDE + ve * 16 + col3]     = a20 + b0;
                actA[fb * FSTRIDE + ve * 16 + col3 + 1] = a21 + b1;
            }
        }
        __syncthreads();   // B4

        // ---- f-L1: 32 -> 128 (leaky), up to 3 batches/thread ----
        if (t < 256) {
            const int f0 = bp * FSTRIDE;
            const int f1 = (bp + 16) * FSTRIDE;
            const int f2 = f_has2 ? (bp + 32) * FSTRIDE : f0;
            float a0[8] = {0,0,0,0,0,0,0,0};
            float a1[8] = {0,0,0,0,0,0,0,0};
            float a2[8] = {0,0,0,0,0,0,0,0};
#pragma unroll
            for (int i4 = 0; i4 < 8; ++i4) {
                const float4 y0 = *(const float4*)&actA[f0 + i4 * 4];
                const float4 y1 = *(const float4*)&actA[f1 + i4 * 4];
                const float4 y2 = *(const float4*)&actA[f2 + i4 * 4];
#pragma unroll
                for (int u = 0; u < 4; ++u) {
                    const int row = (i4 * 4 + u) * 128 + colf;
                    const float4 wA = *(const float4*)&wFa[row];
                    const float4 wB = *(const float4*)&wFa[row + 4];
                    const float v0 = (&y0.x)[u], v1 = (&y1.x)[u], v2 = (&y2.x)[u];
                    a0[0] += v0 * wA.x; a0[1] += v0 * wA.y;
                    a0[2] += v0 * wA.z; a0[3] += v0 * wA.w;
                    a0[4] += v0 * wB.x; a0[5] += v0 * wB.y;
                    a0[6] += v0 * wB.z; a0[7] += v0 * wB.w;
                    a1[0] += v1 * wA.x; a1[1] += v1 * wA.y;
                    a1[2] += v1 * wA.z; a1[3] += v1 * wA.w;
                    a1[4] += v1 * wB.x; a1[5] += v1 * wB.y;
                    a1[6] += v1 * wB.z; a1[7] += v1 * wB.w;
                    a2[0] += v2 * wA.x; a2[1] += v2 * wA.y;
                    a2[2] += v2 * wA.z; a2[3] += v2 * wA.w;
                    a2[4] += v2 * wB.x; a2[5] += v2 * wB.y;
                    a2[6] += v2 * wB.z; a2[7] += v2 * wB.w;
                }
            }
            const float4 bA = *(const float4*)&wFa[4096 + colf];
            const float4 bB = *(const float4*)&wFa[4096 + colf + 4];
            float4 o0, o1;
            o0.x = lrelu(a0[0] + bA.x); o0.y = lrelu(a0[1] + bA.y);
            o0.z = lrelu(a0[2] + bA.z); o0.w = lrelu(a0[3] + bA.w);
            o1.x = lrelu(a0[4] + bB.x); o1.y = lrelu(a0[5] + bB.y);
            o1.z = lrelu(a0[6] + bB.z); o1.w = lrelu(a0[7] + bB.w);
            *(float4*)&actB[f0 + colf]     = o0;
            *(float4*)&actB[f0 + colf + 4] = o1;
            o0.x = lrelu(a1[0] + bA.x); o0.y = lrelu(a1[1] + bA.y);
            o0.z = lrelu(a1[2] + bA.z); o0.w = lrelu(a1[3] + bA.w);
            o1.x = lrelu(a1[4] + bB.x); o1.y = lrelu(a1[5] + bB.y);
            o1.z = lrelu(a1[6] + bB.z); o1.w = lrelu(a1[7] + bB.w);
            *(float4*)&actB[f1 + colf]     = o0;
            *(float4*)&actB[f1 + colf + 4] = o1;
            if (f_has2) {
                o0.x = lrelu(a2[0] + bA.x); o0.y = lrelu(a2[1] + bA.y);
                o0.z = lrelu(a2[2] + bA.z); o0.w = lrelu(a2[3] + bA.w);
                o1.x = lrelu(a2[4] + bB.x); o1.y = lrelu(a2[5] + bB.y);
                o1.z = lrelu(a2[6] + bB.z); o1.w = lrelu(a2[7] + bB.w);
                *(float4*)&actB[f2 + colf]     = o0;
                *(float4*)&actB[f2 + colf + 4] = o1;
            }
        }
        __syncthreads();   // B5

        // ---- f-L2: 128 -> 128 (leaky), fused full-k, weights resident ----
        if (t < 256) {
            const int f0 = bp * FSTRIDE;
            const int f1 = (bp + 16) * FSTRIDE;
            const int f2 = f_has2 ? (bp + 32) * FSTRIDE : f0;
            float a0[8] = {0,0,0,0,0,0,0,0};
            float a1[8] = {0,0,0,0,0,0,0,0};
            float a2[8] = {0,0,0,0,0,0,0,0};
#pragma unroll 4
            for (int i4 = 0; i4 < 16; ++i4) {
                const float4 y0 = *(const float4*)&actB[f0 + i4 * 4];
                const float4 y1 = *(const float4*)&actB[f1 + i4 * 4];
                const float4 y2 = *(const float4*)&actB[f2 + i4 * 4];
#pragma unroll
                for (int u = 0; u < 4; ++u) {
                    const int row = (i4 * 4 + u) * 128 + colf;
                    const float4 wA = *(const float4*)&wH[row];
                    const float4 wB = *(const float4*)&wH[row + 4];
                    const float v0 = (&y0.x)[u], v1 = (&y1.x)[u], v2 = (&y2.x)[u];
                    a0[0] += v0 * wA.x; a0[1] += v0 * wA.y;
                    a0[2] += v0 * wA.z; a0[3] += v0 * wA.w;
                    a0[4] += v0 * wB.x; a0[5] += v0 * wB.y;
                    a0[6] += v0 * wB.z; a0[7] += v0 * wB.w;
                    a1[0] += v1 * wA.x; a1[1] += v1 * wA.y;
                    a1[2] += v1 * wA.z; a1[3] += v1 * wA.w;
                    a1[4] += v1 * wB.x; a1[5] += v1 * wB.y;
                    a1[6] += v1 * wB.z; a1[7] += v1 * wB.w;
                    a2[0] += v2 * wA.x; a2[1] += v2 * wA.y;
                    a2[2] += v2 * wA.z; a2[3] += v2 * wA.w;
                    a2[4] += v2 * wB.x; a2[5] += v2 * wB.y;
                    a2[6] += v2 * wB.z; a2[7] += v2 * wB.w;
                }
            }
#pragma unroll 4
            for (int i4 = 0; i4 < 16; ++i4) {
                const float4 y0 = *(const float4*)&actB[f0 + 64 + i4 * 4];
                const float4 y1 = *(const float4*)&actB[f1 + 64 + i4 * 4];
                const float4 y2 = *(const float4*)&actB[f2 + 64 + i4 * 4];
#pragma unroll
                for (int u = 0; u < 4; ++u) {
                    const int row = (i4 * 4 + u) * 128 + colf;
                    const float4 wA = *(const float4*)&wH2[row];
                    const float4 wB = *(const float4*)&wH2[row + 4];
                    const float v0 = (&y0.x)[u], v1 = (&y1.x)[u], v2 = (&y2.x)[u];
                    a0[0] += v0 * wA.x; a0[1] += v0 * wA.y;
                    a0[2] += v0 * wA.z; a0[3] += v0 * wA.w;
                    a0[4] += v0 * wB.x; a0[5] += v0 * wB.y;
                    a0[6] += v0 * wB.z; a0[7] += v0 * wB.w;
                    a1[0] += v1 * wA.x; a1[1] += v1 * wA.y;
                    a1[2] += v1 * wA.z; a1[3] += v1 * wA.w;
                    a1[4] += v1 * wB.x; a1[5] += v1 * wB.y;
                    a1[6] += v1 * wB.z; a1[7] += v1 * wB.w;
                    a2[0] += v2 * wA.x; a2[1] += v2 * wA.y;
                    a2[2] += v2 * wA.z; a2[3] += v2 * wA.w;
                    a2[4] += v2 * wB.x; a2[5] += v2 * wB.y;
                    a2[6] += v2 * wB.z; a2[7] += v2 * wB.w;
                }
            }
            const float4 bA = *(const float4*)&wFb2[colf];
            const float4 bB = *(const float4*)&wFb2[colf + 4];
            float4 o0, o1;
            o0.x = lrelu(a0[0] + bA.x); o0.y = lrelu(a0[1] + bA.y);
            o0.z = lrelu(a0[2] + bA.z); o0.w = lrelu(a0[3] + bA.w);
            o1.x = lrelu(a0[4] + bB.x); o1.y = lrelu(a0[5] + bB.y);
            o1.z = lrelu(a0[6] + bB.z); o1.w = lrelu(a0[7] + bB.w);
            *(float4*)&actA[f0 + colf]     = o0;
            *(float4*)&actA[f0 + colf + 4] = o1;
            o0.x = lrelu(a1[0] + bA.x); o0.y = lrelu(a1[1] + bA.y);
            o0.z = lrelu(a1[2] + bA.z); o0.w = lrelu(a1[3] + bA.w);
            o1.x = lrelu(a1[4] + bB.x); o1.y = lrelu(a1[5] + bB.y);
            o1.z = lrelu(a1[6] + bB.z); o1.w = lrelu(a1[7] + bB.w);
            *(float4*)&actA[f1 + colf]     = o0;
            *(float4*)&actA[f1 + colf + 4] = o1;
            if (f_has2) {
                o0.x = lrelu(a2[0] + bA.x); o0.y = lrelu(a2[1] + bA.y);
                o0.z = lrelu(a2[2] + bA.z); o0.w = lrelu(a2[3] + bA.w);
                o1.x = lrelu(a2[4] + bB.x); o1.y = lrelu(a2[5] + bB.y);
                o1.z = lrelu(a2[6] + bB.z); o1.w = lrelu(a2[7] + bB.w);
                *(float4*)&actA[f2 + colf]     = o0;
                *(float4*)&actA[f2 + colf + 4] = o1;
            }
        }
        __syncthreads();   // B6

        // ---- f-L3: 128 -> 8 (no act) + sin/cos; 1 batch/thread (t<352) ----
        if (fb3 < CAP) {
            const int ib = pb + fb3;
            if (ib < hi) {
                const int foff = fb3 * FSTRIDE;
                const int wb = col8 * 132;
                float a = 0.f;
#pragma unroll 8
                for (int i4 = 0; i4 < 32; ++i4) {
                    const float4 y4 = *(const float4*)&actA[foff + i4 * 4];
                    const float4 w4 = *(const float4*)&wT[wb + i4 * 4];
                    a += y4.x * w4.x + y4.y * w4.y + y4.z * w4.z + y4.w * w4.w;
                }
                a += wFb3[col8];
                const int bi = perm[base + ib];
                out[(size_t)bi * 16 + col8]     = __sinf(a);
                out[(size_t)bi * 16 + 8 + col8] = __cosf(a);
            }
        }
    }
}

// ---------------------------------------------------------------------------
extern "C" void kernel_launch(void* const* d_in, const int* in_sizes, int n_in,
                              void* d_out, int out_size, void* d_ws, size_t ws_size,
                              hipStream_t stream)
{
    const int*   indices = (const int*)  d_in[0];
    const float* states  = (const float*)d_in[1];
    const float* maps    = (const float*)d_in[2];
    const float* fc1_w   = (const float*)d_in[3];
    const float* fc1_b   = (const float*)d_in[4];
    const float* fc2_w   = (const float*)d_in[5];
    const float* fc2_b   = (const float*)d_in[6];
    const float* fc3_w   = (const float*)d_in[7];
    const float* fc3_b   = (const float*)d_in[8];
    const float* bn_w    = (const float*)d_in[9];
    const float* bn_b    = (const float*)d_in[10];
    const float* e_w     = (const float*)d_in[11];
    const float* e_b     = (const float*)d_in[12];
    const float* f_w     = (const float*)d_in[13];
    const float* f_b     = (const float*)d_in[14];
    float* out = (float*)d_out;

    float* ws   = (float*)d_ws;
    float* z    = ws;                    // 2048
    float* th_e = ws + 2048;             // 349184
    float* th_f = ws + 351232;           // 1393152
    int* counts  = (int*)(ws + 1744384); // 64
    int* offsets = counts + 64;          // 64
    int* perm    = counts + 128;         // 8192
    float* h1g   = ws + 1752704;         // 16384

    static int s_lds_optin = 0;
    if (!s_lds_optin) {
        hipFuncSetAttribute((const void*)func_kernel,
                            hipFuncAttributeMaxDynamicSharedMemorySize,
                            K3_LDS_BYTES);
        s_lds_optin = 1;
    }

    fc1_kernel<<<256, 1024, 0, stream>>>(maps, fc1_w, fc1_b, h1g);
    backbone_bucket_kernel<<<65, 1024, 0, stream>>>(
        h1g, fc2_w, fc2_b, fc3_w, fc3_b, bn_w, bn_b, z,
        indices, counts, offsets, perm);
    theta_kernel<<<dim3(107, 8), 256, 0, stream>>>(
        z, e_w, e_b, f_w, f_b, th_e, th_f);
    func_kernel<<<dim3(NCLS, 4), 512, K3_LDS_BYTES, stream>>>(
        states, th_e, th_f, counts, offsets, perm, out);
}

// Round 8
// 129.504 us; speedup vs baseline: 1.1497x; 1.1497x over previous
//
#include <hip/hip_runtime.h>
#include <hip/hip_bf16.h>

// ============================================================================
// indices ∈ [0,64) => backbone + theta have only 64 distinct rows. Compute
// per-class (7 MB, L2-resident), bucket batches by class, run only the tiny
// per-batch MLPs with class-shared weights.
// R12 = R11 resubmitted (previous round failed on container infra, no data).
// K3 = proven v7 structure (R7, 130.5us total: 128KB LDS, W2f streamed
// through one 32KB buffer twice per pass, CAP 48, reg-roundtrip staging).
// Single delta vs R7: W3f additionally staged TRANSPOSED (wT[col][k], stride
// 132, +4.2KB -> 132.3KB) so f-L3 weight reads are 32 ds_read_b128 instead
// of 128 ds_read_b32 per thread. K0/K1/K2 unchanged.
// ============================================================================

#define LEAKY 0.2f
#define NCLS 64
#define B_TOT 8192
#define CAP 48            // batches per K3 pass (capacity)

// theta_e (per class, 5456 fl): W1e[0,128) b1e[128,192) W2e[192,4288)
//   b2e[4288,4352) W3e[4352,5376) b3e[5376,5392)
// theta_f (per class, 21768 fl): W1f[0,4096) b1f[4096,4224) W2f[4224,20608)
//   b2f[20608,20736) W3f[20736,21760) b3f[21760,21768)

__device__ __forceinline__ float lrelu(float x) { return x >= 0.f ? x : LEAKY * x; }

// ---------------------------------------------------------------------------
// K0: fc1 1024->256 split over 256 blocks: block = (class c = bx>>2, quarter
// q = bx&3). 1024 thr: o = q*64 + (t&63), 16 K-slices of 64.
// ---------------------------------------------------------------------------
__global__ __launch_bounds__(1024) void fc1_kernel(
    const float* __restrict__ maps, const float* __restrict__ fc1_w,
    const float* __restrict__ fc1_b, float* __restrict__ h1g)
{
    __shared__ float m[1024];
    __shared__ float red[1024];
    const int t = threadIdx.x;
    const int c = blockIdx.x >> 2;
    const int q = blockIdx.x & 3;

    m[t] = maps[(size_t)c * 1024 + t];
    __syncthreads();

    const int ol = t & 63, ks = t >> 6;
    const int o = q * 64 + ol;
    const float* wp = fc1_w + o;
    float acc = 0.f;
#pragma unroll 8
    for (int i = 0; i < 64; ++i) {
        const int k = ks * 64 + i;
        acc += m[k] * wp[(size_t)k * 256];
    }
    red[t] = acc;
    __syncthreads();
    if (t < 64) {
        float a = fc1_b[q * 64 + t];
#pragma unroll
        for (int r = 0; r < 16; ++r) a += red[r * 64 + t];
        h1g[c * 256 + q * 64 + t] = lrelu(a);
    }
}

// ---------------------------------------------------------------------------
// K1: blocks 0..63: fc2+fc3+bn for class c (h1 from ws). block 64: bucket.
// ---------------------------------------------------------------------------
__global__ __launch_bounds__(1024) void backbone_bucket_kernel(
    const float* __restrict__ h1g,
    const float* __restrict__ fc2_w, const float* __restrict__ fc2_b,
    const float* __restrict__ fc3_w, const float* __restrict__ fc3_b,
    const float* __restrict__ bn_w,  const float* __restrict__ bn_b,
    float* __restrict__ z,
    const int* __restrict__ idx, int* __restrict__ counts,
    int* __restrict__ offsets, int* __restrict__ perm)
{
    __shared__ float red[1024];
    __shared__ float h1[256];
    __shared__ float h2[128];
    __shared__ float h3[128];
    __shared__ int cnt[16][64];
    __shared__ int wcur[16][64];

    const int t = threadIdx.x;

    if (blockIdx.x == 64) {
        // ---------------- bucket ----------------
        const int w = t >> 6;
        cnt[w][t & 63] = 0;
        __syncthreads();
        int my[8];
#pragma unroll
        for (int r = 0; r < 8; ++r) {
            my[r] = idx[r * 1024 + t];
            atomicAdd(&cnt[w][my[r]], 1);
        }
        __syncthreads();
        if (t < 64) {
            int run = 0;
#pragma unroll
            for (int w2 = 0; w2 < 16; ++w2) {
                const int v = cnt[w2][t];
                wcur[w2][t] = run;
                run += v;
            }
            counts[t] = run;
            int x = run;
            for (int d = 1; d < 64; d <<= 1) {
                const int y = __shfl_up(x, d, 64);
                if (t >= d) x += y;
            }
            const int basec = x - run;
            offsets[t] = basec;
#pragma unroll
            for (int w2 = 0; w2 < 16; ++w2) wcur[w2][t] += basec;
        }
        __syncthreads();
#pragma unroll
        for (int r = 0; r < 8; ++r) {
            const int p = atomicAdd(&wcur[w][my[r]], 1);
            perm[p] = r * 1024 + t;
        }
        return;
    }

    // ---------------- fc2/fc3/bn for class c ----------------
    const int c = blockIdx.x;
    if (t < 256) h1[t] = h1g[c * 256 + t];
    __syncthreads();

    // fc2: 256 -> 128 (leaky)
    {
        const int o = t & 127, ks = t >> 7;
        float acc = 0.f;
#pragma unroll
        for (int i = 0; i < 32; ++i) {
            const int k = ks * 32 + i;
            acc += h1[k] * fc2_w[k * 128 + o];
        }
        red[t] = acc;
    }
    __syncthreads();
    if (t < 128) {
        float a = fc2_b[t];
#pragma unroll
        for (int r = 0; r < 8; ++r) a += red[r * 128 + t];
        h2[t] = lrelu(a);
    }
    __syncthreads();
    // fc3: 128 -> 128 (leaky)
    {
        const int o = t & 127, ks = t >> 7;
        float acc = 0.f;
#pragma unroll
        for (int i = 0; i < 16; ++i) {
            const int k = ks * 16 + i;
            acc += h2[k] * fc3_w[k * 128 + o];
        }
        red[t] = acc;
    }
    __syncthreads();
    if (t < 128) {
        float a = fc3_b[t];
#pragma unroll
        for (int r = 0; r < 8; ++r) a += red[r * 128 + t];
        h3[t] = lrelu(a);
    }
    __syncthreads();
    // bn: 128 -> 32 (no act)
    {
        const int o = t & 31, ks = t >> 5;
        float acc = 0.f;
#pragma unroll
        for (int i = 0; i < 4; ++i) {
            const int k = ks * 4 + i;
            acc += h3[k] * bn_w[k * 32 + o];
        }
        red[t] = acc;
    }
    __syncthreads();
    if (t < 32) {
        float a = bn_b[t];
#pragma unroll
        for (int r = 0; r < 32; ++r) a += red[r * 32 + t];
        z[c * 32 + t] = a;
    }
}

// ---------------------------------------------------------------------------
// K2: theta, grid (107, 8): block owns 256 cols x 8 classes. Weights in regs.
// ---------------------------------------------------------------------------
__global__ __launch_bounds__(256) void theta_kernel(
    const float* __restrict__ z,
    const float* __restrict__ e_w, const float* __restrict__ e_b,
    const float* __restrict__ f_w, const float* __restrict__ f_b,
    float* __restrict__ th_e, float* __restrict__ th_f)
{
    __shared__ __align__(16) float zl[2048];
    const int t = threadIdx.x;
    ((float4*)zl)[t]       = ((const float4*)z)[t];
    ((float4*)zl)[t + 256] = ((const float4*)z)[t + 256];
    __syncthreads();

    int j = blockIdx.x * 256 + t;
    const int cbase = blockIdx.y * 8;
    const float* wbase;
    float* op;
    int stride;
    float bias;
    if (j < 5456) {
        wbase = e_w + j; bias = e_b[j]; op = th_e + j; stride = 5456;
    } else {
        const int jj = j - 5456;
        if (jj >= 21768) return;
        wbase = f_w + jj; bias = f_b[jj]; op = th_f + jj; stride = 21768;
    }
    float wk[32];
#pragma unroll
    for (int k = 0; k < 32; ++k) wk[k] = wbase[(size_t)k * stride];

#pragma unroll
    for (int cc = 0; cc < 8; cc += 4) {
        const int c0 = cbase + cc;
        float a0 = bias, a1 = bias, a2 = bias, a3 = bias;
#pragma unroll
        for (int k4 = 0; k4 < 8; ++k4) {
            const float4 z0 = *(const float4*)&zl[(c0 + 0) * 32 + k4 * 4];
            const float4 z1 = *(const float4*)&zl[(c0 + 1) * 32 + k4 * 4];
            const float4 z2 = *(const float4*)&zl[(c0 + 2) * 32 + k4 * 4];
            const float4 z3 = *(const float4*)&zl[(c0 + 3) * 32 + k4 * 4];
            const float w0 = wk[k4 * 4], w1 = wk[k4 * 4 + 1];
            const float w2 = wk[k4 * 4 + 2], w3 = wk[k4 * 4 + 3];
            a0 += z0.x * w0 + z0.y * w1 + z0.z * w2 + z0.w * w3;
            a1 += z1.x * w0 + z1.y * w1 + z1.z * w2 + z1.w * w3;
            a2 += z2.x * w0 + z2.y * w1 + z2.z * w2 + z2.w * w3;
            a3 += z3.x * w0 + z3.y * w1 + z3.z * w2 + z3.w * w3;
        }
        op[(size_t)(c0 + 0) * stride] = a0;
        op[(size_t)(c0 + 1) * stride] = a1;
        op[(size_t)(c0 + 2) * stride] = a2;
        op[(size_t)(c0 + 3) * stride] = a3;
    }
}

// ---------------------------------------------------------------------------
// K3: func v11 = v7 + W3f-transposed f-L3. grid (64, 4), 512 thr. Slice s =
// balanced ~nb/4 chunk, one pass of capacity 48 (3 batches/thread).
// LDS (floats): wE[5392] | wFa[5384] | wH[8192] | actA[6528] | actB[6528]
//   | wT[1056] = 33080 fl = 132320 B (dynamic). wFa = W1f+b1f|b2f|W3f|b3f.
//   wH = current 64-K-row half of W2f, staged twice per pass (streaming).
//   wT = W3f transposed: [col]*132 + k (conflict-free b128 reads in f-L3).
// e phases (t<256): eg = t&7 (8 col groups of 8), vp = t>>3; vb = vp+{0,32,64}
//   (vb = batch*2 + state). f phases (t<256): bp = t&15, fg = t>>4 (16 groups
//   of 8); fb = bp+{0,16,32}. f-L3 (t<384): col = t&7, fb3 = t>>3.
// ---------------------------------------------------------------------------
#define ESTRIDE 68   // 17 float4s, odd
#define FSTRIDE 132  // 33 float4s, odd

#define K3_LDS_FLOATS 33080
#define K3_LDS_BYTES  (K3_LDS_FLOATS * 4)

__global__ __launch_bounds__(512) void func_kernel(
    const float* __restrict__ states,
    const float* __restrict__ th_e_all, const float* __restrict__ th_f_all,
    const int* __restrict__ counts, const int* __restrict__ offsets,
    const int* __restrict__ perm, float* __restrict__ out)
{
    extern __shared__ float smem[];
    float* wE   = smem;             // 5392
    float* wFa  = smem + 5392;      // 5384
    float* wH   = smem + 10776;     // 8192
    float* actA = smem + 18968;     // 6528
    float* actB = smem + 25496;     // 6528
    float* wT   = smem + 32024;     // 1056

    const int c = blockIdx.x;
    const int s = blockIdx.y;
    const int nb   = counts[c];
    const int base = offsets[c];
    const int q = nb >> 2, r = nb & 3;
    const int lo  = s * q + (s < r ? s : r);
    const int cnt = q + (s < r ? 1 : 0);
    if (cnt == 0) return;
    const int hi = lo + cnt;

    const float* te = th_e_all + (size_t)c * 5456;
    const float* tf = th_f_all + (size_t)c * 21768;

    const int t  = threadIdx.x;
    const int eg = t & 7,  vp = t >> 3;    // e mapping (valid t<256)
    const int bp = t & 15, fg = t >> 4;    // f mapping (valid t<256)
    const int cole = eg * 8;
    const int colf = fg * 8;
    const int col8 = t & 7, fb3 = t >> 3;  // f-L3 mapping (valid t<384)

    // ---- stage persistent weights once ----
    for (int j = t * 4; j < 5392; j += 2048)
        *(float4*)&wE[j] = *(const float4*)&te[j];
    for (int j = t * 4; j < 4224; j += 2048)
        *(float4*)&wFa[j] = *(const float4*)&tf[j];
    for (int j = t * 4; j < 1160; j += 2048)
        *(float4*)&wFa[4224 + j] = *(const float4*)&tf[20608 + j];
    for (int j = t; j < 1024; j += 512)                      // W3f transposed
        wT[(j & 7) * 132 + (j >> 3)] = tf[20736 + j];

    const int npass = (cnt + CAP - 1) / CAP;   // 1 in practice
    for (int p = 0; p < npass; ++p) {
        __syncthreads();   // B1: staging visible / prev-pass reads done

        // stage W2f half 0 (k rows 0..63) — consumed after B5
        for (int j = t * 4; j < 8192; j += 2048)
            *(float4*)&wH[j] = *(const float4*)&tf[4224 + j];

        const int pb = lo + p * CAP;   // first class-local batch this pass

        // ---- e-L1: 2 -> 64 (leaky), 3 vb/thread ----
        if (t < 256) {
            const float4 wa0 = *(const float4*)&wE[cole];
            const float4 wa1 = *(const float4*)&wE[cole + 4];
            const float4 wb0 = *(const float4*)&wE[64 + cole];
            const float4 wb1 = *(const float4*)&wE[64 + cole + 4];
            const float4 bb0 = *(const float4*)&wE[128 + cole];
            const float4 bb1 = *(const float4*)&wE[128 + cole + 4];
#pragma unroll
            for (int sub = 0; sub < 3; ++sub) {
                const int vb = vp + 32 * sub;
                const int fb = vb >> 1, ve = vb & 1;
                const int ib = pb + fb;
                const int bi = (ib < hi) ? perm[base + ib] : 0;
                const float2 sv = *(const float2*)&states[(size_t)bi * 4 + 2 * ve];
                float4 o0, o1;
                o0.x = lrelu(sv.x * wa0.x + sv.y * wb0.x + bb0.x);
                o0.y = lrelu(sv.x * wa0.y + sv.y * wb0.y + bb0.y);
                o0.z = lrelu(sv.x * wa0.z + sv.y * wb0.z + bb0.z);
                o0.w = lrelu(sv.x * wa0.w + sv.y * wb0.w + bb0.w);
                o1.x = lrelu(sv.x * wa1.x + sv.y * wb1.x + bb1.x);
                o1.y = lrelu(sv.x * wa1.y + sv.y * wb1.y + bb1.y);
                o1.z = lrelu(sv.x * wa1.z + sv.y * wb1.z + bb1.z);
                o1.w = lrelu(sv.x * wa1.w + sv.y * wb1.w + bb1.w);
                *(float4*)&actA[vb * ESTRIDE + cole]     = o0;
                *(float4*)&actA[vb * ESTRIDE + cole + 4] = o1;
            }
        }
        __syncthreads();   // B2

        // ---- e-L2: 64 -> 64 (leaky), 3 vb/thread ----
        if (t < 256) {
            const int e0 = vp * ESTRIDE;
            const int e1 = (vp + 32) * ESTRIDE;
            const int e2 = (vp + 64) * ESTRIDE;
            float a0[8] = {0,0,0,0,0,0,0,0};
            float a1[8] = {0,0,0,0,0,0,0,0};
            float a2[8] = {0,0,0,0,0,0,0,0};
#pragma unroll 4
            for (int i4 = 0; i4 < 16; ++i4) {
                const float4 y0 = *(const float4*)&actA[e0 + i4 * 4];
                const float4 y1 = *(const float4*)&actA[e1 + i4 * 4];
                const float4 y2 = *(const float4*)&actA[e2 + i4 * 4];
#pragma unroll
                for (int u = 0; u < 4; ++u) {
                    const int row = 192 + (i4 * 4 + u) * 64 + cole;
                    const float4 wA = *(const float4*)&wE[row];
                    const float4 wB = *(const float4*)&wE[row + 4];
                    const float v0 = (&y0.x)[u], v1 = (&y1.x)[u], v2 = (&y2.x)[u];
                    a0[0] += v0 * wA.x; a0[1] += v0 * wA.y;
                    a0[2] += v0 * wA.z; a0[3] += v0 * wA.w;
                    a0[4] += v0 * wB.x; a0[5] += v0 * wB.y;
                    a0[6] += v0 * wB.z; a0[7] += v0 * wB.w;
                    a1[0] += v1 * wA.x; a1[1] += v1 * wA.y;
                    a1[2] += v1 * wA.z; a1[3] += v1 * wA.w;
                    a1[4] += v1 * wB.x; a1[5] += v1 * wB.y;
                    a1[6] += v1 * wB.z; a1[7] += v1 * wB.w;
                    a2[0] += v2 * wA.x; a2[1] += v2 * wA.y;
                    a2[2] += v2 * wA.z; a2[3] += v2 * wA.w;
                    a2[4] += v2 * wB.x; a2[5] += v2 * wB.y;
                    a2[6] += v2 * wB.z; a2[7] += v2 * wB.w;
                }
            }
            const float4 bA = *(const float4*)&wE[4288 + cole];
            const float4 bB = *(const float4*)&wE[4288 + cole + 4];
            float4 o0, o1;
            o0.x = lrelu(a0[0] + bA.x); o0.y = lrelu(a0[1] + bA.y);
            o0.z = lrelu(a0[2] + bA.z); o0.w = lrelu(a0[3] + bA.w);
            o1.x = lrelu(a0[4] + bB.x); o1.y = lrelu(a0[5] + bB.y);
            o1.z = lrelu(a0[6] + bB.z); o1.w = lrelu(a0[7] + bB.w);
            *(float4*)&actB[e0 + cole]     = o0;
            *(float4*)&actB[e0 + cole + 4] = o1;
            o0.x = lrelu(a1[0] + bA.x); o0.y = lrelu(a1[1] + bA.y);
            o0.z = lrelu(a1[2] + bA.z); o0.w = lrelu(a1[3] + bA.w);
            o1.x = lrelu(a1[4] + bB.x); o1.y = lrelu(a1[5] + bB.y);
            o1.z = lrelu(a1[6] + bB.z); o1.w = lrelu(a1[7] + bB.w);
            *(float4*)&actB[e1 + cole]     = o0;
            *(float4*)&actB[e1 + cole + 4] = o1;
            o0.x = lrelu(a2[0] + bA.x); o0.y = lrelu(a2[1] + bA.y);
            o0.z = lrelu(a2[2] + bA.z); o0.w = lrelu(a2[3] + bA.w);
            o1.x = lrelu(a2[4] + bB.x); o1.y = lrelu(a2[5] + bB.y);
            o1.z = lrelu(a2[6] + bB.z); o1.w = lrelu(a2[7] + bB.w);
            *(float4*)&actB[e2 + cole]     = o0;
            *(float4*)&actB[e2 + cole + 4] = o1;
        }
        __syncthreads();   // B3

        // ---- e-L3: 64 -> 16 (no act) -> zf (f-layout in actA) ----
        if (t < 256) {
            const int col3 = eg * 2;
            const int e0 = vp * ESTRIDE;
            const int e1 = (vp + 32) * ESTRIDE;
            const int e2 = (vp + 64) * ESTRIDE;
            float a00 = 0.f, a01 = 0.f, a10 = 0.f, a11 = 0.f, a20 = 0.f, a21 = 0.f;
#pragma unroll 4
            for (int i4 = 0; i4 < 16; ++i4) {
                const float4 y0 = *(const float4*)&actB[e0 + i4 * 4];
                const float4 y1 = *(const float4*)&actB[e1 + i4 * 4];
                const float4 y2 = *(const float4*)&actB[e2 + i4 * 4];
#pragma unroll
                for (int u = 0; u < 4; ++u) {
                    const float2 w2 = *(const float2*)&wE[4352 + (i4 * 4 + u) * 16 + col3];
                    const float v0 = (&y0.x)[u], v1 = (&y1.x)[u], v2 = (&y2.x)[u];
                    a00 += v0 * w2.x; a01 += v0 * w2.y;
                    a10 += v1 * w2.x; a11 += v1 * w2.y;
                    a20 += v2 * w2.x; a21 += v2 * w2.y;
                }
            }
            const float b0 = wE[5376 + col3], b1 = wE[5376 + col3 + 1];
            {
                const int vb = vp, fb = vb >> 1, ve = vb & 1;
                actA[fb * FSTRIDE + ve * 16 + col3]     = a00 + b0;
                actA[fb * FSTRIDE + ve * 16 + col3 + 1] = a01 + b1;
            }
            {
                const int vb = vp + 32, fb = vb >> 1, ve = vb & 1;
                actA[fb * FSTRIDE + ve * 16 + col3]     = a10 + b0;
                actA[fb * FSTRIDE + ve * 16 + col3 + 1] = a11 + b1;
            }
            {
                const int vb = vp + 64, fb = vb >> 1, ve = vb & 1;
                actA[fb * FSTRIDE + ve * 16 + col3]     = a20 + b0;
                actA[fb * FSTRIDE + ve * 16 + col3 + 1] = a21 + b1;
            }
        }
        __syncthreads();   // B4

        // ---- f-L1: 32 -> 128 (leaky), 3 batches/thread ----
        if (t < 256) {
            const int f0 = bp * FSTRIDE;
            const int f1 = (bp + 16) * FSTRIDE;
            const int f2 = (bp + 32) * FSTRIDE;
            float a0[8] = {0,0,0,0,0,0,0,0};
            float a1[8] = {0,0,0,0,0,0,0,0};
            float a2[8] = {0,0,0,0,0,0,0,0};
#pragma unroll
            for (int i4 = 0; i4 < 8; ++i4) {
                const float4 y0 = *(const float4*)&actA[f0 + i4 * 4];
                const float4 y1 = *(const float4*)&actA[f1 + i4 * 4];
                const float4 y2 = *(const float4*)&actA[f2 + i4 * 4];
#pragma unroll
                for (int u = 0; u < 4; ++u) {
                    const int row = (i4 * 4 + u) * 128 + colf;
                    const float4 wA = *(const float4*)&wFa[row];
                    const float4 wB = *(const float4*)&wFa[row + 4];
                    const float v0 = (&y0.x)[u], v1 = (&y1.x)[u], v2 = (&y2.x)[u];
                    a0[0] += v0 * wA.x; a0[1] += v0 * wA.y;
                    a0[2] += v0 * wA.z; a0[3] += v0 * wA.w;
                    a0[4] += v0 * wB.x; a0[5] += v0 * wB.y;
                    a0[6] += v0 * wB.z; a0[7] += v0 * wB.w;
                    a1[0] += v1 * wA.x; a1[1] += v1 * wA.y;
                    a1[2] += v1 * wA.z; a1[3] += v1 * wA.w;
                    a1[4] += v1 * wB.x; a1[5] += v1 * wB.y;
                    a1[6] += v1 * wB.z; a1[7] += v1 * wB.w;
                    a2[0] += v2 * wA.x; a2[1] += v2 * wA.y;
                    a2[2] += v2 * wA.z; a2[3] += v2 * wA.w;
                    a2[4] += v2 * wB.x; a2[5] += v2 * wB.y;
                    a2[6] += v2 * wB.z; a2[7] += v2 * wB.w;
                }
            }
            const float4 bA = *(const float4*)&wFa[4096 + colf];
            const float4 bB = *(const float4*)&wFa[4096 + colf + 4];
            float4 o0, o1;
            o0.x = lrelu(a0[0] + bA.x); o0.y = lrelu(a0[1] + bA.y);
            o0.z = lrelu(a0[2] + bA.z); o0.w = lrelu(a0[3] + bA.w);
            o1.x = lrelu(a0[4] + bB.x); o1.y = lrelu(a0[5] + bB.y);
            o1.z = lrelu(a0[6] + bB.z); o1.w = lrelu(a0[7] + bB.w);
            *(float4*)&actB[f0 + colf]     = o0;
            *(float4*)&actB[f0 + colf + 4] = o1;
            o0.x = lrelu(a1[0] + bA.x); o0.y = lrelu(a1[1] + bA.y);
            o0.z = lrelu(a1[2] + bA.z); o0.w = lrelu(a1[3] + bA.w);
            o1.x = lrelu(a1[4] + bB.x); o1.y = lrelu(a1[5] + bB.y);
            o1.z = lrelu(a1[6] + bB.z); o1.w = lrelu(a1[7] + bB.w);
            *(float4*)&actB[f1 + colf]     = o0;
            *(float4*)&actB[f1 + colf + 4] = o1;
            o0.x = lrelu(a2[0] + bA.x); o0.y = lrelu(a2[1] + bA.y);
            o0.z = lrelu(a2[2] + bA.z); o0.w = lrelu(a2[3] + bA.w);
            o1.x = lrelu(a2[4] + bB.x); o1.y = lrelu(a2[5] + bB.y);
            o1.z = lrelu(a2[6] + bB.z); o1.w = lrelu(a2[7] + bB.w);
            *(float4*)&actB[f2 + colf]     = o0;
            *(float4*)&actB[f2 + colf + 4] = o1;
        }
        __syncthreads();   // B5

        // ---- f-L2: 128 -> 128 (leaky), W2f in 2 staged K-halves ----
        {
            const int f0 = bp * FSTRIDE;
            const int f1 = (bp + 16) * FSTRIDE;
            const int f2 = (bp + 32) * FSTRIDE;
            float a0[8] = {0,0,0,0,0,0,0,0};
            float a1[8] = {0,0,0,0,0,0,0,0};
            float a2[8] = {0,0,0,0,0,0,0,0};
            if (t < 256) {
#pragma unroll 4
                for (int i4 = 0; i4 < 16; ++i4) {
                    const float4 y0 = *(const float4*)&actB[f0 + i4 * 4];
                    const float4 y1 = *(const float4*)&actB[f1 + i4 * 4];
                    const float4 y2 = *(const float4*)&actB[f2 + i4 * 4];
#pragma unroll
                    for (int u = 0; u < 4; ++u) {
                        const int row = (i4 * 4 + u) * 128 + colf;
                        const float4 wA = *(const float4*)&wH[row];
                        const float4 wB = *(const float4*)&wH[row + 4];
                        const float v0 = (&y0.x)[u], v1 = (&y1.x)[u], v2 = (&y2.x)[u];
                        a0[0] += v0 * wA.x; a0[1] += v0 * wA.y;
                        a0[2] += v0 * wA.z; a0[3] += v0 * wA.w;
                        a0[4] += v0 * wB.x; a0[5] += v0 * wB.y;
                        a0[6] += v0 * wB.z; a0[7] += v0 * wB.w;
                        a1[0] += v1 * wA.x; a1[1] += v1 * wA.y;
                        a1[2] += v1 * wA.z; a1[3] += v1 * wA.w;
                        a1[4] += v1 * wB.x; a1[5] += v1 * wB.y;
                        a1[6] += v1 * wB.z; a1[7] += v1 * wB.w;
                        a2[0] += v2 * wA.x; a2[1] += v2 * wA.y;
                        a2[2] += v2 * wA.z; a2[3] += v2 * wA.w;
                        a2[4] += v2 * wB.x; a2[5] += v2 * wB.y;
                        a2[6] += v2 * wB.z; a2[7] += v2 * wB.w;
                    }
                }
            }
            __syncthreads();   // B6: wH half-0 reads done
            for (int j = t * 4; j < 8192; j += 2048)
                *(float4*)&wH[j] = *(const float4*)&tf[4224 + 8192 + j];
            __syncthreads();   // B7: half 1 visible
            if (t < 256) {
#pragma unroll 4
                for (int i4 = 0; i4 < 16; ++i4) {
                    const float4 y0 = *(const float4*)&actB[f0 + 64 + i4 * 4];
                    const float4 y1 = *(const float4*)&actB[f1 + 64 + i4 * 4];
                    const float4 y2 = *(const float4*)&actB[f2 + 64 + i4 * 4];
#pragma unroll
                    for (int u = 0; u < 4; ++u) {
                        const int row = (i4 * 4 + u) * 128 + colf;
                        const float4 wA = *(const float4*)&wH[row];
                        const float4 wB = *(const float4*)&wH[row + 4];
                        const float v0 = (&y0.x)[u], v1 = (&y1.x)[u], v2 = (&y2.x)[u];
                        a0[0] += v0 * wA.x; a0[1] += v0 * wA.y;
                        a0[2] += v0 * wA.z; a0[3] += v0 * wA.w;
                        a0[4] += v0 * wB.x; a0[5] += v0 * wB.y;
                        a0[6] += v0 * wB.z; a0[7] += v0 * wB.w;
                        a1[0] += v1 * wA.x; a1[1] += v1 * wA.y;
                        a1[2] += v1 * wA.z; a1[3] += v1 * wA.w;
                        a1[4] += v1 * wB.x; a1[5] += v1 * wB.y;
                        a1[6] += v1 * wB.z; a1[7] += v1 * wB.w;
                        a2[0] += v2 * wA.x; a2[1] += v2 * wA.y;
                        a2[2] += v2 * wA.z; a2[3] += v2 * wA.w;
                        a2[4] += v2 * wB.x; a2[5] += v2 * wB.y;
                        a2[6] += v2 * wB.z; a2[7] += v2 * wB.w;
                    }
                }
                const float4 bA = *(const float4*)&wFa[4224 + colf];
                const float4 bB = *(const float4*)&wFa[4224 + colf + 4];
                float4 o0, o1;
                o0.x = lrelu(a0[0] + bA.x); o0.y = lrelu(a0[1] + bA.y);
                o0.z = lrelu(a0[2] + bA.z); o0.w = lrelu(a0[3] + bA.w);
                o1.x = lrelu(a0[4] + bB.x); o1.y = lrelu(a0[5] + bB.y);
                o1.z = lrelu(a0[6] + bB.z); o1.w = lrelu(a0[7] + bB.w);
                *(float4*)&actA[f0 + colf]     = o0;
                *(float4*)&actA[f0 + colf + 4] = o1;
                o0.x = lrelu(a1[0] + bA.x); o0.y = lrelu(a1[1] + bA.y);
                o0.z = lrelu(a1[2] + bA.z); o0.w = lrelu(a1[3] + bA.w);
                o1.x = lrelu(a1[4] + bB.x); o1.y = lrelu(a1[5] + bB.y);
                o1.z = lrelu(a1[6] + bB.z); o1.w = lrelu(a1[7] + bB.w);
                *(float4*)&actA[f1 + colf]     = o0;
                *(float4*)&actA[f1 + colf + 4] = o1;
                o0.x = lrelu(a2[0] + bA.x); o0.y = lrelu(a2[1] + bA.y);
                o0.z = lrelu(a2[2] + bA.z); o0.w = lrelu(a2[3] + bA.w);
                o1.x = lrelu(a2[4] + bB.x); o1.y = lrelu(a2[5] + bB.y);
                o1.z = lrelu(a2[6] + bB.z); o1.w = lrelu(a2[7] + bB.w);
                *(float4*)&actA[f2 + colf]     = o0;
                *(float4*)&actA[f2 + colf + 4] = o1;
            }
        }
        __syncthreads();   // B8

        // ---- f-L3: 128 -> 8 (no act) + sin/cos; 1 batch/thread (t<384) ----
        if (fb3 < CAP) {
            const int ib = pb + fb3;
            if (ib < hi) {
                const int foff = fb3 * FSTRIDE;
                const int wb = col8 * 132;
                float a = 0.f;
#pragma unroll 8
                for (int i4 = 0; i4 < 32; ++i4) {
                    const float4 y4 = *(const float4*)&actA[foff + i4 * 4];
                    const float4 w4 = *(const float4*)&wT[wb + i4 * 4];
                    a += y4.x * w4.x + y4.y * w4.y + y4.z * w4.z + y4.w * w4.w;
                }
                a += wFa[5376 + col8];
                const int bi = perm[base + ib];
                out[(size_t)bi * 16 + col8]     = __sinf(a);
                out[(size_t)bi * 16 + 8 + col8] = __cosf(a);
            }
        }
    }
}

// ---------------------------------------------------------------------------
extern "C" void kernel_launch(void* const* d_in, const int* in_sizes, int n_in,
                              void* d_out, int out_size, void* d_ws, size_t ws_size,
                              hipStream_t stream)
{
    const int*   indices = (const int*)  d_in[0];
    const float* states  = (const float*)d_in[1];
    const float* maps    = (const float*)d_in[2];
    const float* fc1_w   = (const float*)d_in[3];
    const float* fc1_b   = (const float*)d_in[4];
    const float* fc2_w   = (const float*)d_in[5];
    const float* fc2_b   = (const float*)d_in[6];
    const float* fc3_w   = (const float*)d_in[7];
    const float* fc3_b   = (const float*)d_in[8];
    const float* bn_w    = (const float*)d_in[9];
    const float* bn_b    = (const float*)d_in[10];
    const float* e_w     = (const float*)d_in[11];
    const float* e_b     = (const float*)d_in[12];
    const float* f_w     = (const float*)d_in[13];
    const float* f_b     = (const float*)d_in[14];
    float* out = (float*)d_out;

    float* ws   = (float*)d_ws;
    float* z    = ws;                    // 2048
    float* th_e = ws + 2048;             // 349184
    float* th_f = ws + 351232;           // 1393152
    int* counts  = (int*)(ws + 1744384); // 64
    int* offsets = counts + 64;          // 64
    int* perm    = counts + 128;         // 8192
    float* h1g   = ws + 1752704;         // 16384

    static int s_lds_optin = 0;
    if (!s_lds_optin) {
        hipFuncSetAttribute((const void*)func_kernel,
                            hipFuncAttributeMaxDynamicSharedMemorySize,
                            K3_LDS_BYTES);
        s_lds_optin = 1;
    }

    fc1_kernel<<<256, 1024, 0, stream>>>(maps, fc1_w, fc1_b, h1g);
    backbone_bucket_kernel<<<65, 1024, 0, stream>>>(
        h1g, fc2_w, fc2_b, fc3_w, fc3_b, bn_w, bn_b, z,
        indices, counts, offsets, perm);
    theta_kernel<<<dim3(107, 8), 256, 0, stream>>>(
        z, e_w, e_b, f_w, f_b, th_e, th_f);
    func_kernel<<<dim3(NCLS, 4), 512, K3_LDS_BYTES, stream>>>(
        states, th_e, th_f, counts, offsets, perm, out);
}